// Round 8
// baseline (1912.704 us; speedup 1.0000x reference)
//
#include <hip/hip_runtime.h>

#define BATCH 4
#define SEQ   4096
#define NEMBD 384
#define HDIM  64
// 64^-0.5 * log2(e): q pre-scaled so softmax works in exp2 domain
#define QSCALE 0.18033688011112042f
#define NEG_BIG (-1.0e30f)
#define DEFER_THR 8.0f
#define EXP2F(x) __builtin_amdgcn_exp2f(x)

// ---------------- QKV projection v2: LDS-staged x, fused 3-mat GEMM ----------
// Block = 512 threads, M-tile = 32 rows. LDS = 32x384 floats (48 KB).
// Thread (c = tid&63, rg = tid>>6): computes rows rg*4..rg*4+3, col c, for
// q,k,v simultaneously (12 accumulators). x reads from LDS are wave-uniform
// broadcasts; W reads are 256 B coalesced and L2-hot.
__global__ __launch_bounds__(512) void qkv_proj_kernel(
    const float* __restrict__ x,
    const float* __restrict__ Wq,
    const float* __restrict__ Wk,
    const float* __restrict__ Wv,
    float* __restrict__ q,
    float* __restrict__ k,
    float* __restrict__ v)
{
    __shared__ float xs[32][NEMBD];            // 48 KB
    const int tid  = threadIdx.x;
    const long row0 = (long)blockIdx.x * 32;

    // stage x tile: 12288 floats = 3072 float4 = 512 threads x 6
    {
        const float4* xg = (const float4*)(x + row0*NEMBD);
        float4* xl = (float4*)&xs[0][0];
#pragma unroll
        for (int i = 0; i < 6; ++i)
            xl[tid + i*512] = xg[tid + i*512];
    }
    __syncthreads();

    const int c  = tid & 63;
    const int rg = tid >> 6;                   // 0..7 -> 4 rows each
    float aq[4], ak[4], av[4];
#pragma unroll
    for (int r = 0; r < 4; ++r) { aq[r]=0.f; ak[r]=0.f; av[r]=0.f; }

#pragma unroll 2
    for (int k4 = 0; k4 < NEMBD/4; ++k4) {
        const int kk = k4*4;
        float4 xr[4];
#pragma unroll
        for (int r = 0; r < 4; ++r)
            xr[r] = *(const float4*)&xs[rg*4 + r][kk];
#pragma unroll
        for (int j = 0; j < 4; ++j) {
            const float wq = Wq[(kk+j)*HDIM + c];
            const float wk = Wk[(kk+j)*HDIM + c];
            const float wv = Wv[(kk+j)*HDIM + c];
#pragma unroll
            for (int r = 0; r < 4; ++r) {
                const float xc = (j==0)?xr[r].x:(j==1)?xr[r].y:(j==2)?xr[r].z:xr[r].w;
                aq[r] = fmaf(xc, wq, aq[r]);
                ak[r] = fmaf(xc, wk, ak[r]);
                av[r] = fmaf(xc, wv, av[r]);
            }
        }
    }
#pragma unroll
    for (int r = 0; r < 4; ++r) {
        const long o = (row0 + rg*4 + r)*HDIM + c;
        q[o] = aq[r];
        k[o] = ak[r];
        v[o] = av[r];
    }
}

// ---------------- causal flash attention v4: LDS-free, global-direct --------
// No __shared__, no barriers. Wave = 32 q-rows x 2 lanes/row (lane owns 32
// dims). K/V rows are wave-uniform per key -> read straight from L2 (2 MB per
// batch, hot). Split-K: part p handles contiguous keys [p*C, p*C+C).
// Softmax: defer-max (THR=8) in exp2 domain; masked keys get p=0 explicitly.
__global__ __launch_bounds__(256, 4) void attn_kernel(
    const float* __restrict__ Q,
    const float* __restrict__ K,
    const float* __restrict__ V,
    float* __restrict__ opart,
    float* __restrict__ mlpart,
    const int S, const int C)
{
    const int gid  = blockIdx.x;
    const int part = gid % S;
    const int rest = gid / S;
    const int b    = rest & 3;
    const int qt   = 31 - (rest >> 2);         // 128-row group, longest first
    const int tid  = threadIdx.x;
    const int w    = tid >> 6;                 // wave 0..3 (independent)
    const int lane = tid & 63;
    const int g    = lane >> 1;                // row in strip 0..31
    const int sub  = lane & 1;                 // dim half
    const int R0   = qt*128 + w*32;
    const int row  = R0 + g;

    const int kbeg = part * C;
    const int kend = min(R0 + 32, kbeg + C);   // both even

    const long rowoff = (long)b*SEQ + row;
    float* op = opart + ((long)part*BATCH*SEQ + rowoff)*HDIM + sub*32;

    if (kbeg >= kend) {                        // empty part: neutral partials
        const float4 z = {0.f, 0.f, 0.f, 0.f};
#pragma unroll
        for (int j = 0; j < 8; ++j) *(float4*)(op + j*4) = z;
        if (sub == 0) {
            float2 ml; ml.x = NEG_BIG; ml.y = 0.f;
            *(float2*)&mlpart[((long)part*BATCH*SEQ + rowoff)*2] = ml;
        }
        return;
    }

    // q fragment: this lane's 32 dims, pre-scaled into exp2 domain
    float4 qv[8];
    {
        const float* qp = Q + rowoff*HDIM + sub*32;
#pragma unroll
        for (int j = 0; j < 8; ++j) {
            float4 t = *(const float4*)(qp + j*4);
            qv[j].x = t.x*QSCALE; qv[j].y = t.y*QSCALE;
            qv[j].z = t.z*QSCALE; qv[j].w = t.w*QSCALE;
        }
    }
    float4 ov[8];
#pragma unroll
    for (int j = 0; j < 8; ++j) { ov[j].x=0.f; ov[j].y=0.f; ov[j].z=0.f; ov[j].w=0.f; }
    float m = NEG_BIG, l = 0.f;

    const float* Kb = K + (long)b*SEQ*HDIM + sub*32;
    const float* Vb = V + (long)b*SEQ*HDIM + sub*32;

#pragma unroll 2
    for (int key = kbeg; key < kend; ++key) {
        // K row (this lane's half), wave has only 2 unique addresses
        const float4* kp = (const float4*)(Kb + (long)key*HDIM);
        float4 kf[8];
#pragma unroll
        for (int j = 0; j < 8; ++j) kf[j] = kp[j];

        float s = 0.f;
#pragma unroll
        for (int j = 0; j < 8; ++j) {
            s = fmaf(qv[j].x, kf[j].x, s);
            s = fmaf(qv[j].y, kf[j].y, s);
            s = fmaf(qv[j].z, kf[j].z, s);
            s = fmaf(qv[j].w, kf[j].w, s);
        }
        s += __shfl_xor(s, 1);

        const bool valid = (key <= row);
        s = valid ? s : NEG_BIG;

        if (__any(s > m + DEFER_THR)) {        // rare; wave-uniform branch
            const float newm = fmaxf(m, s);
            const float scale = EXP2F(m - newm);
            l *= scale;
#pragma unroll
            for (int j = 0; j < 8; ++j) {
                ov[j].x *= scale; ov[j].y *= scale;
                ov[j].z *= scale; ov[j].w *= scale;
            }
            m = newm;
        }
        // p-mask (not s-mask): guards fully-masked lanes where m==NEG_BIG
        const float p = valid ? EXP2F(s - m) : 0.f;
        l += p;

        const float4* vp = (const float4*)(Vb + (long)key*HDIM);
#pragma unroll
        for (int j = 0; j < 8; ++j) {
            const float4 vf = vp[j];
            ov[j].x = fmaf(p, vf.x, ov[j].x);
            ov[j].y = fmaf(p, vf.y, ov[j].y);
            ov[j].z = fmaf(p, vf.z, ov[j].z);
            ov[j].w = fmaf(p, vf.w, ov[j].w);
        }
    }

#pragma unroll
    for (int j = 0; j < 8; ++j) *(float4*)(op + j*4) = ov[j];
    if (sub == 0) {
        float2 ml; ml.x = m; ml.y = l;
        *(float2*)&mlpart[((long)part*BATCH*SEQ + rowoff)*2] = ml;
    }
}

// ---------------- split-K combine (S parts, exp2 domain) ----------------
__global__ __launch_bounds__(256) void combine_kernel(
    const float* __restrict__ opart,
    const float* __restrict__ mlpart,
    float* __restrict__ out,
    const int S)
{
    const int tid  = threadIdx.x;
    const int d    = tid & 63;
    const int rsub = tid >> 6;                      // 0..3
    const long row = (long)blockIdx.x * 4 + rsub;
    const long PERO = (long)BATCH * SEQ * HDIM;
    const long PERM = (long)BATCH * SEQ;

    float M = NEG_BIG;
    for (int p = 0; p < S; ++p)
        M = fmaxf(M, mlpart[((long)p*PERM + row)*2]);

    float L = 0.f, acc = 0.f;
    for (int p = 0; p < S; ++p) {
        const float2 ml = *(const float2*)&mlpart[((long)p*PERM + row)*2];
        const float e = EXP2F(ml.x - M);            // 0 for empty parts
        L   = fmaf(ml.y, e, L);
        acc = fmaf(opart[(long)p*PERO + row*HDIM + d], e, acc);
    }
    out[row*HDIM + d] = acc / L;
}

extern "C" void kernel_launch(void* const* d_in, const int* in_sizes, int n_in,
                              void* d_out, int out_size, void* d_ws, size_t ws_size,
                              hipStream_t stream) {
    const float* x  = (const float*)d_in[0];
    const float* Wq = (const float*)d_in[1];
    const float* Wk = (const float*)d_in[2];
    const float* Wv = (const float*)d_in[3];
    float* out = (float*)d_out;

    const size_t PER  = (size_t)BATCH * SEQ * HDIM;   // 1M floats
    const size_t PERM = (size_t)BATCH * SEQ;          // 16K rows

    // split-K factor adapted to workspace: need (3 + S)*PER + S*PERM*2 floats
    int S = 16;
    while (S > 1 && (3*PER + (size_t)S*PER + (size_t)S*PERM*2)*4 > ws_size) S >>= 1;
    const int C = SEQ / S;

    float* qws    = (float*)d_ws;
    float* kws    = qws + PER;
    float* vws    = kws + PER;
    float* opart  = vws + PER;                 // S * PER floats
    float* mlpart = opart + (size_t)S*PER;     // S * PERM * 2 floats

    qkv_proj_kernel<<<BATCH*SEQ/32, 512, 0, stream>>>(x, Wq, Wk, Wv, qws, kws, vws);
    attn_kernel<<<S*BATCH*32, 256, 0, stream>>>(qws, kws, vws, opart, mlpart, S, C);
    combine_kernel<<<BATCH*SEQ/4, 256, 0, stream>>>(opart, mlpart, out, S);
}

// Round 10
// 310.472 us; speedup vs baseline: 6.1606x; 6.1606x over previous
//
#include <hip/hip_runtime.h>

#define BATCH 4
#define SEQ   4096
#define NEMBD 384
#define HDIM  64
#define KBLK  64
// 64^-0.5 * log2(e): q pre-scaled so softmax works in exp2 domain
#define QSCALE 0.18033688011112042f
#define NEG_BIG (-1.0e30f)
#define DEFER_THR 8.0f
#define EXP2F(x) __builtin_amdgcn_exp2f(x)

// ---------------- QKV projection: LDS-staged x, fused 3-mat GEMM ----------
__global__ __launch_bounds__(512) void qkv_proj_kernel(
    const float* __restrict__ x,
    const float* __restrict__ Wq,
    const float* __restrict__ Wk,
    const float* __restrict__ Wv,
    float* __restrict__ q,
    float* __restrict__ k,
    float* __restrict__ v)
{
    __shared__ float xs[32][NEMBD];            // 48 KB
    const int tid  = threadIdx.x;
    const long row0 = (long)blockIdx.x * 32;

    {
        const float4* xg = (const float4*)(x + row0*NEMBD);
        float4* xl = (float4*)&xs[0][0];
#pragma unroll
        for (int i = 0; i < 6; ++i)
            xl[tid + i*512] = xg[tid + i*512];
    }
    __syncthreads();

    const int c  = tid & 63;
    const int rg = tid >> 6;                   // 0..7 -> 4 rows each
    float aq[4], ak[4], av[4];
#pragma unroll
    for (int r = 0; r < 4; ++r) { aq[r]=0.f; ak[r]=0.f; av[r]=0.f; }

#pragma unroll 2
    for (int k4 = 0; k4 < NEMBD/4; ++k4) {
        const int kk = k4*4;
        float4 xr[4];
#pragma unroll
        for (int r = 0; r < 4; ++r)
            xr[r] = *(const float4*)&xs[rg*4 + r][kk];
#pragma unroll
        for (int jj = 0; jj < 4; ++jj) {
            const float wq = Wq[(kk+jj)*HDIM + c];
            const float wk = Wk[(kk+jj)*HDIM + c];
            const float wv = Wv[(kk+jj)*HDIM + c];
#pragma unroll
            for (int r = 0; r < 4; ++r) {
                const float xc = (jj==0)?xr[r].x:(jj==1)?xr[r].y:(jj==2)?xr[r].z:xr[r].w;
                aq[r] = fmaf(xc, wq, aq[r]);
                ak[r] = fmaf(xc, wk, ak[r]);
                av[r] = fmaf(xc, wv, av[r]);
            }
        }
    }
#pragma unroll
    for (int r = 0; r < 4; ++r) {
        const long o = (row0 + rg*4 + r)*HDIM + c;
        q[o] = aq[r];
        k[o] = ak[r];
        v[o] = av[r];
    }
}

// 8-lane sum reduce entirely on the VALU via DPP: xor1 (quad_perm 0xB1),
// xor2 (quad_perm 0x4E), then row_half_mirror (0x141, lane ^= 7 within 8).
// {1,2,7} generates the full 8-lane group; no ds_swizzle -> no LDS pipe use.
__device__ __forceinline__ float red8(float x) {
    int t = __builtin_amdgcn_update_dpp(0, __float_as_int(x), 0xB1, 0xF, 0xF, true);
    x += __int_as_float(t);
    t = __builtin_amdgcn_update_dpp(0, __float_as_int(x), 0x4E, 0xF, 0xF, true);
    x += __int_as_float(t);
    t = __builtin_amdgcn_update_dpp(0, __float_as_int(x), 0x141, 0xF, 0xF, true);
    x += __int_as_float(t);
    return x;
}

// ---------------- causal flash attention v5 ----------------
// Wave = 8 row-quads x 8 lanes. Lane (g = lane>>3, j = lane&7) owns rows
// r0..r0+3 (r0 = Rw + 4g) and dims j*8..j*8+7. Per key: 4 ds_read_b128
// (K half + V half, each serving 4 rows) -> LDS pipe no longer the limit.
// Dot closed over 8 lanes by DPP adds. Defer-max softmax in exp2 domain;
// causal mask applied on p only (unmasked s in the max is still valid math).
// Interleaved split-K: part p takes tiles kt = p, p+S, ...

#define KEYSTEP(MASKED)                                                        \
  {                                                                            \
    const float4 ka = *(const float4*)&Ks[kk][j8];                             \
    const float4 kb = *(const float4*)&Ks[kk][j8 + 4];                         \
    float s[4];                                                                \
    _Pragma("unroll")                                                          \
    for (int r = 0; r < 4; ++r) {                                              \
      float acc =       qa[r].x * ka.x;                                        \
      acc = fmaf(qa[r].y, ka.y, acc);                                          \
      acc = fmaf(qa[r].z, ka.z, acc);                                          \
      acc = fmaf(qa[r].w, ka.w, acc);                                          \
      acc = fmaf(qb[r].x, kb.x, acc);                                          \
      acc = fmaf(qb[r].y, kb.y, acc);                                          \
      acc = fmaf(qb[r].z, kb.z, acc);                                          \
      acc = fmaf(qb[r].w, kb.w, acc);                                          \
      s[r] = red8(acc);                                                        \
    }                                                                          \
    const float c = fmaxf(fmaxf(s[0]-m[0], s[1]-m[1]),                         \
                          fmaxf(s[2]-m[2], s[3]-m[3]));                        \
    if (__any(c > DEFER_THR)) {              /* rare */                        \
      _Pragma("unroll")                                                        \
      for (int r = 0; r < 4; ++r) {                                            \
        const float nm = fmaxf(m[r], s[r]);                                    \
        const float sc = EXP2F(m[r] - nm);                                     \
        m[r] = nm; l[r] *= sc;                                                 \
        oa[r].x *= sc; oa[r].y *= sc; oa[r].z *= sc; oa[r].w *= sc;            \
        ob[r].x *= sc; ob[r].y *= sc; ob[r].z *= sc; ob[r].w *= sc;            \
      }                                                                        \
    }                                                                          \
    const float4 va = *(const float4*)&Vs[kk][j8];                             \
    const float4 vb = *(const float4*)&Vs[kk][j8 + 4];                         \
    _Pragma("unroll")                                                          \
    for (int r = 0; r < 4; ++r) {                                              \
      float p = EXP2F(s[r] - m[r]);                                            \
      if (MASKED) p = (base + kk <= r0 + r) ? p : 0.f;                         \
      l[r] += p;                                                               \
      oa[r].x = fmaf(p, va.x, oa[r].x); oa[r].y = fmaf(p, va.y, oa[r].y);      \
      oa[r].z = fmaf(p, va.z, oa[r].z); oa[r].w = fmaf(p, va.w, oa[r].w);      \
      ob[r].x = fmaf(p, vb.x, ob[r].x); ob[r].y = fmaf(p, vb.y, ob[r].y);      \
      ob[r].z = fmaf(p, vb.z, ob[r].z); ob[r].w = fmaf(p, vb.w, ob[r].w);      \
    }                                                                          \
  }

__global__ __launch_bounds__(256, 4) void attn_kernel(
    const float* __restrict__ Q,
    const float* __restrict__ K,
    const float* __restrict__ V,
    float* __restrict__ opart,
    float* __restrict__ mlpart,
    const int S)
{
    __shared__ float Ks[KBLK][HDIM];
    __shared__ float Vs[KBLK][HDIM];

    const int gid  = blockIdx.x;
    const int part = gid % S;
    const int rest = gid / S;
    const int b    = rest & 3;
    const int qt   = 31 - (rest >> 2);      // 128-row tile, longest first
    const int q0   = qt * 128;
    const int tid  = threadIdx.x;
    const int w    = tid >> 6;              // wave 0..3
    const int lane = tid & 63;
    const int g    = lane >> 3;             // row-quad 0..7
    const int j8   = (lane & 7) * 8;        // dim octet base
    const int Rw   = q0 + w*32;             // wave's first row
    const int r0   = Rw + g*4;              // lane's first row
    const int wmax = Rw + 31;

    // q fragments: 4 rows x 8 dims, pre-scaled into exp2 domain
    float4 qa[4], qb[4];
    {
        const float* qp = Q + ((long)b*SEQ + r0)*HDIM + j8;
#pragma unroll
        for (int r = 0; r < 4; ++r) {
            float4 t = *(const float4*)(qp + r*HDIM);
            qa[r].x = t.x*QSCALE; qa[r].y = t.y*QSCALE;
            qa[r].z = t.z*QSCALE; qa[r].w = t.w*QSCALE;
            t = *(const float4*)(qp + r*HDIM + 4);
            qb[r].x = t.x*QSCALE; qb[r].y = t.y*QSCALE;
            qb[r].z = t.z*QSCALE; qb[r].w = t.w*QSCALE;
        }
    }
    float4 oa[4], ob[4];
    float m[4], l[4];
#pragma unroll
    for (int r = 0; r < 4; ++r) {
        oa[r].x=0.f; oa[r].y=0.f; oa[r].z=0.f; oa[r].w=0.f;
        ob[r].x=0.f; ob[r].y=0.f; ob[r].z=0.f; ob[r].w=0.f;
        m[r] = NEG_BIG; l[r] = 0.f;
    }

    const float* Kb = K + (long)b*SEQ*HDIM;
    const float* Vb = V + (long)b*SEQ*HDIM;
    const int ntiles = (q0 + 128) / KBLK;   // 2*(qt+1), block-uniform

    for (int kt = part; kt < ntiles; kt += S) {
        __syncthreads();
        {
            const float4* Kg = (const float4*)(Kb + (long)kt*KBLK*HDIM);
            const float4* Vg = (const float4*)(Vb + (long)kt*KBLK*HDIM);
            float4* Ksw = (float4*)&Ks[0][0];
            float4* Vsw = (float4*)&Vs[0][0];
#pragma unroll
            for (int i = 0; i < 4; ++i) {
                Ksw[tid + i*256] = Kg[tid + i*256];
                Vsw[tid + i*256] = Vg[tid + i*256];
            }
        }
        __syncthreads();

        const int base = kt * KBLK;
        if (base > wmax) continue;          // wave idle for this tile

        if (base + KBLK <= Rw) {
            // fully-causal tile: no masking
            for (int kk = 0; kk < KBLK; ++kk) KEYSTEP(false)
        } else {
            // (partially) diagonal tile: mask p per row
            const int kkend = Rw + 32 - base;   // max lim over the wave
            for (int kk = 0; kk < kkend; ++kk) KEYSTEP(true)
        }
    }

    const long PERM = (long)BATCH * SEQ;
    const long obase = ((long)part*PERM + (long)b*SEQ + r0)*HDIM + j8;
#pragma unroll
    for (int r = 0; r < 4; ++r) {
        *(float4*)(opart + obase + r*HDIM)     = oa[r];
        *(float4*)(opart + obase + r*HDIM + 4) = ob[r];
    }
    if (j8 == 0) {
#pragma unroll
        for (int r = 0; r < 4; ++r) {
            float2 ml; ml.x = m[r]; ml.y = l[r];
            *(float2*)&mlpart[((long)part*PERM + (long)b*SEQ + r0 + r)*2] = ml;
        }
    }
}

// ---------------- split-K combine (S parts, exp2 domain) ----------------
__global__ __launch_bounds__(256) void combine_kernel(
    const float* __restrict__ opart,
    const float* __restrict__ mlpart,
    float* __restrict__ out,
    const int S)
{
    const int tid  = threadIdx.x;
    const int d    = tid & 63;
    const int rsub = tid >> 6;                      // 0..3
    const long row = (long)blockIdx.x * 4 + rsub;
    const long PERO = (long)BATCH * SEQ * HDIM;
    const long PERM = (long)BATCH * SEQ;

    float M = NEG_BIG;
    for (int p = 0; p < S; ++p)
        M = fmaxf(M, mlpart[((long)p*PERM + row)*2]);

    float L = 0.f, acc = 0.f;
    for (int p = 0; p < S; ++p) {
        const float2 ml = *(const float2*)&mlpart[((long)p*PERM + row)*2];
        const float e = EXP2F(ml.x - M);            // 0 for empty parts
        L   = fmaf(ml.y, e, L);
        acc = fmaf(opart[(long)p*PERO + row*HDIM + d], e, acc);
    }
    out[row*HDIM + d] = acc / L;
}

extern "C" void kernel_launch(void* const* d_in, const int* in_sizes, int n_in,
                              void* d_out, int out_size, void* d_ws, size_t ws_size,
                              hipStream_t stream) {
    const float* x  = (const float*)d_in[0];
    const float* Wq = (const float*)d_in[1];
    const float* Wk = (const float*)d_in[2];
    const float* Wv = (const float*)d_in[3];
    float* out = (float*)d_out;

    const size_t PER  = (size_t)BATCH * SEQ * HDIM;   // 1M floats
    const size_t PERM = (size_t)BATCH * SEQ;          // 16K rows

    int S = 8;
    while (S > 1 && (3*PER + (size_t)S*PER + (size_t)S*PERM*2)*4 > ws_size) S >>= 1;

    float* qws    = (float*)d_ws;
    float* kws    = qws + PER;
    float* vws    = kws + PER;
    float* opart  = vws + PER;                 // S * PER floats
    float* mlpart = opart + (size_t)S*PER;     // S * PERM * 2 floats

    qkv_proj_kernel<<<BATCH*SEQ/32, 512, 0, stream>>>(x, Wq, Wk, Wv, qws, kws, vws);
    attn_kernel<<<S*BATCH*(SEQ/128), 256, 0, stream>>>(qws, kws, vws, opart, mlpart, S);
    combine_kernel<<<BATCH*SEQ/4, 256, 0, stream>>>(opart, mlpart, out, S);
}